// Round 19
// baseline (97.210 us; speedup 1.0000x reference)
//
#include <hip/hip_runtime.h>

#define NEG_INF (-3.402823466e+38f)

constexpr int Bc = 8, Cc = 512, Hc = 8, Dc = 64, Nc = 1024;
constexpr size_t QSZ = (size_t)Bc * Hc * Nc * Dc;  // 4,194,304 elements
constexpr size_t XTSZ = (size_t)8192 * 512;        // = QSZ
constexpr size_t WTSZ = (size_t)1536 * 512;

typedef __attribute__((ext_vector_type(8))) short short8;
typedef __attribute__((ext_vector_type(4))) float f32x4;
typedef unsigned short ushort_t;
typedef unsigned int uint_t;

// ------------------------------------------------------------ bf16 helpers
__device__ __forceinline__ ushort_t f2bf(float x) {
  uint_t u = __float_as_uint(x);
  u += 0x7FFFu + ((u >> 16) & 1u);  // round-to-nearest-even
  return (ushort_t)(u >> 16);
}
__device__ __forceinline__ float bf2f(ushort_t h) {
  return __uint_as_float(((uint_t)h) << 16);
}

// ------------------------------------- transpose x -> xt (bf16) + zero out
__global__ __launch_bounds__(256) void conv_x(const float* __restrict__ x,
                                              ushort_t* __restrict__ xh,
                                              float* __restrict__ out) {
  __shared__ float t[64][65];
  const int b = blockIdx.z, c0 = blockIdx.y * 64, n0 = blockIdx.x * 64;
  const int tid = threadIdx.x;
  const int lc = tid & 63, lr = tid >> 6;
  int fb = (blockIdx.z * 8 + blockIdx.y) * 16 + blockIdx.x;
  if (fb < 16) out[fb * 256 + tid] = 0.f;
#pragma unroll
  for (int i = 0; i < 16; ++i) {
    int cc = lr + i * 4;
    t[cc][lc] = x[((size_t)(b * 512 + c0 + cc)) * 1024 + n0 + lc];
  }
  __syncthreads();
#pragma unroll
  for (int i = 0; i < 16; ++i) {
    int nn = lr + i * 4;
    xh[((size_t)(b * 1024 + n0 + nn)) * 512 + c0 + lc] = f2bf(t[lc][nn]);
  }
}

// ---------------------------------- transpose+split W -> wt hi/lo (bf16 x2)
// lo is skipped for V columns (j >= 1024): V runs 1-pass in the GEMM.
__global__ __launch_bounds__(256) void conv_w(const float* __restrict__ wq,
                                              ushort_t* __restrict__ wh,
                                              ushort_t* __restrict__ wl) {
  __shared__ float t[64][65];
  const int c0 = blockIdx.y * 64, j0 = blockIdx.x * 64;
  const int tid = threadIdx.x;
  const int lj = tid & 63, lr = tid >> 6;
#pragma unroll
  for (int i = 0; i < 16; ++i) {
    int cc = lr + i * 4;
    t[cc][lj] = wq[(size_t)(c0 + cc) * 1536 + j0 + lj];
  }
  __syncthreads();
#pragma unroll
  for (int i = 0; i < 16; ++i) {
    int jj = lr + i * 4;
    float v = t[lj][jj];  // = W[c0+lj][j0+jj]
    ushort_t h = f2bf(v);
    size_t o = (size_t)(j0 + jj) * 512 + c0 + lj;
    wh[o] = h;
    if (j0 < 1024) wl[o] = f2bf(v - bf2f(h));
  }
}

// ------------------------------------------------------ async stage helper
__device__ __forceinline__ void stage_tile(ushort_t* lds, const ushort_t* g,
                                           int tid) {
  typedef const __attribute__((address_space(1))) unsigned int GU;
  typedef __attribute__((address_space(3))) unsigned int LU;
  {
    int l = tid, r = l >> 2, c = (l & 3) * 8;
    __builtin_amdgcn_global_load_lds((GU*)(g + (size_t)r * 512 + c),
                                     (LU*)(lds + (size_t)l * 8), 16, 0, 0);
  }
  {
    int l = tid + 256, r = l >> 2, c = (l & 3) * 8;
    __builtin_amdgcn_global_load_lds((GU*)(g + (size_t)r * 512 + c),
                                     (LU*)(lds + (size_t)l * 8), 16, 0, 0);
  }
}

// ---------------------------------------------------------------- QKV GEMM
// Q/K: 2-pass C = x_bf*(W_hi+W_lo), value err ~0.002 (fp32 out for rescore).
// V: 1-pass bf16 out (out sums w*v*q over 1024 tokens -> dv~0.004 adds only
// ~0.03 to absmax). which is block-uniform -> uniform branches.
__global__ __launch_bounds__(256) void qkv_gemm_mfma(
    const ushort_t* __restrict__ xth, const ushort_t* __restrict__ wth,
    const ushort_t* __restrict__ wtl, const float* __restrict__ bias,
    ushort_t* __restrict__ vbf, float* __restrict__ kf, float* __restrict__ qf,
    ushort_t* __restrict__ khi, ushort_t* __restrict__ qhi) {
  __shared__ __align__(16) ushort_t Ah[128 * 32];
  __shared__ __align__(16) ushort_t Bh[128 * 32];
  __shared__ __align__(16) ushort_t Bl[128 * 32];

  const int m0 = blockIdx.x * 128, j0 = blockIdx.y * 128;
  const int tid = threadIdx.x;
  const int w = tid >> 6, l = tid & 63;
  const int lr = l & 15, lg = l >> 4;
  const int wr = w >> 1, wc = w & 1;
  const int which = j0 >> 9;  // 0=q 1=k 2=v (block-uniform)

  f32x4 acc[4][4];
#pragma unroll
  for (int i = 0; i < 4; ++i)
#pragma unroll
    for (int j = 0; j < 4; ++j) acc[i][j] = (f32x4){0.f, 0.f, 0.f, 0.f};

  const ushort_t* xa = xth + (size_t)m0 * 512;
  const ushort_t* wa = wth + (size_t)j0 * 512;
  const ushort_t* wb = wtl + (size_t)j0 * 512;

  for (int s = 0; s < 16; ++s) {
    const int k0 = s * 32;
    stage_tile(Ah, xa + k0, tid);
    stage_tile(Bh, wa + k0, tid);
    if (which != 2) stage_tile(Bl, wb + k0, tid);
    __syncthreads();  // drains vmcnt -> tiles resident

    short8 ah[4], bh[4], bl[4];
#pragma unroll
    for (int mi = 0; mi < 4; ++mi)
      ah[mi] = *(const short8*)&Ah[(wr * 64 + mi * 16 + lr) * 32 + lg * 8];
#pragma unroll
    for (int ji = 0; ji < 4; ++ji) {
      int ro = (wc * 64 + ji * 16 + lr) * 32 + lg * 8;
      bh[ji] = *(const short8*)&Bh[ro];
      bl[ji] = *(const short8*)&Bl[ro];
    }
    if (which != 2) {
#pragma unroll
      for (int mi = 0; mi < 4; ++mi)
#pragma unroll
        for (int ji = 0; ji < 4; ++ji) {
          acc[mi][ji] = __builtin_amdgcn_mfma_f32_16x16x32_bf16(
              ah[mi], bh[ji], acc[mi][ji], 0, 0, 0);
          acc[mi][ji] = __builtin_amdgcn_mfma_f32_16x16x32_bf16(
              ah[mi], bl[ji], acc[mi][ji], 0, 0, 0);
        }
    } else {
#pragma unroll
      for (int mi = 0; mi < 4; ++mi)
#pragma unroll
        for (int ji = 0; ji < 4; ++ji)
          acc[mi][ji] = __builtin_amdgcn_mfma_f32_16x16x32_bf16(
              ah[mi], bh[ji], acc[mi][ji], 0, 0, 0);
    }
    __syncthreads();
  }

  const int hh = ((j0 >> 6) + wc) & 7;
  float bias_r[4];
#pragma unroll
  for (int ji = 0; ji < 4; ++ji) bias_r[ji] = bias[j0 + wc * 64 + ji * 16 + lr];

#pragma unroll
  for (int mi = 0; mi < 4; ++mi)
#pragma unroll
    for (int t = 0; t < 4; ++t) {
      int m = m0 + wr * 64 + mi * 16 + lg * 4 + t;
      int b = m >> 10, n = m & 1023;
      size_t rb = ((size_t)(b * 8 + hh) << 16) + (size_t)n * 64;
#pragma unroll
      for (int ji = 0; ji < 4; ++ji) {
        float val = acc[mi][ji][t] + bias_r[ji];
        int dd = ji * 16 + lr;
        if (which == 2) {
          vbf[rb + dd] = f2bf(val);
        } else if (which == 0) {
          qhi[rb + dd] = f2bf(val);
          qf[rb + dd] = val;
        } else {
          khi[rb + dd] = f2bf(val);
          kf[rb + dd] = val;
        }
      }
    }
}

// -------------------------------------------- float-domain packed-key top-4
__device__ __forceinline__ float packkey(float s, uint_t j) {
  return __uint_as_float((__float_as_uint(s) & 0xFFFFFC00u) | j);
}

// sort 4 keys descending (5-comparator network, depth 3)
__device__ __forceinline__ void sort4f(float& a, float& b, float& c,
                                       float& d) {
  float t;
  t = fmaxf(a, b); b = fminf(a, b); a = t;
  t = fmaxf(c, d); d = fminf(c, d); c = t;
  t = fmaxf(a, c); c = fminf(a, c); a = t;
  t = fmaxf(b, d); d = fminf(b, d); b = t;
  t = fmaxf(b, c); c = fminf(b, c); b = t;
}

// state s0>=s1>=s2>=s3; cand a>=b>=c>=d. Bitonic keep-top-4 + resort.
__device__ __forceinline__ void merge44f(float& s0, float& s1, float& s2,
                                         float& s3, float a, float b, float c,
                                         float d) {
  s0 = fmaxf(s0, d); s1 = fmaxf(s1, c); s2 = fmaxf(s2, b); s3 = fmaxf(s3, a);
  float t;
  t = fmaxf(s0, s2); s2 = fminf(s0, s2); s0 = t;
  t = fmaxf(s1, s3); s3 = fminf(s1, s3); s1 = t;
  t = fmaxf(s0, s1); s1 = fminf(s0, s1); s0 = t;
  t = fmaxf(s2, s3); s3 = fminf(s2, s3); s2 = t;
}

// -------------------------------------------------------- float insert4
__device__ __forceinline__ void insert4(float sc, int jv, float& s0, float& s1,
                                        float& s2, float& s3, int& i0, int& i1,
                                        int& i2, int& i3) {
  bool c = sc > s3;
  s3 = c ? sc : s3; i3 = c ? jv : i3;
  c = s3 > s2;
  { float t = c ? s2 : s3; s2 = c ? s3 : s2; s3 = t;
    int q = c ? i2 : i3; i2 = c ? i3 : i2; i3 = q; }
  c = s2 > s1;
  { float t = c ? s1 : s2; s1 = c ? s2 : s1; s2 = t;
    int q = c ? i1 : i2; i1 = c ? i2 : i1; i2 = q; }
  c = s1 > s0;
  { float t = c ? s0 : s1; s0 = c ? s1 : s0; s1 = t;
    int q = c ? i0 : i1; i0 = c ? i1 : i0; i1 = q; }
}

// ------------------------------------ stage one 128j x 64d K chunk (16 KB)
__device__ __forceinline__ void stage_k_chunk(ushort_t* kt,
                                              const ushort_t* gk, int chunk,
                                              int tid) {
  typedef const __attribute__((address_space(1))) unsigned int GU;
  typedef __attribute__((address_space(3))) unsigned int LU;
#pragma unroll
  for (int ri = 0; ri < 2; ++ri) {
    int p = ri * 512 + tid;      // 0..1023
    int row = p >> 3;            // 0..127 (j within chunk)
    int colu = (p & 7) << 3;     // ushort col: 0,8,..,56
    int srcu = (chunk * 128 + row) * 64 + (colu ^ ((row & 7) << 3));
    __builtin_amdgcn_global_load_lds((GU*)(gk + srcu),
                                     (LU*)(kt + (size_t)p * 8), 16, 0, 0);
  }
}

// ---------------------------------------------------------------- fused attn
// R18 structure (grid 512, 128 rows/block, 8 waves, counted-vmcnt 3-buffer
// pipeline). Stage C now gathers bf16 v (half bytes, more L2-resident).
__global__ __launch_bounds__(512, 6) void attn_topk_mfma(
    const ushort_t* __restrict__ khi, const ushort_t* __restrict__ qhi,
    const float* __restrict__ kf, const float* __restrict__ qf,
    const ushort_t* __restrict__ vbf, float* __restrict__ out) {
  __shared__ __align__(16) ushort_t KT[3][128 * 64];  // 3 x 16 KB
  __shared__ uint_t kLp[128][9];  // pad 9: kill stride-8 bank conflicts
  __shared__ float scS[128][9];
  __shared__ float wgt[128][4];
  __shared__ int widx[128][4];

  const int bid = blockIdx.x;
  const int bh = bid & 63;
  const int rg = bid >> 6;  // 0..7
  const int tid = threadIdx.x;
  const int w = tid >> 6, l = tid & 63;
  const int lg = l >> 4, lr = l & 15;

  const int bhbase = bh << 16;           // bh * 1024 * 64
  const int rowbase = rg * 128 + w * 16; // wave's first q-row (global in bh)
  const ushort_t* gk = khi + bhbase;

  // Q fragments: 1 rowset x 2 d-chunks
  short8 qh[2];
#pragma unroll
  for (int c2 = 0; c2 < 2; ++c2)
    qh[c2] = *(const short8*)(qhi + bhbase + (rowbase + lr) * 64 + c2 * 32 +
                              lg * 8);

  float Ka[4], Kb[4];
#pragma unroll
  for (int t = 0; t < 4; ++t) { Ka[t] = NEG_INF; Kb[t] = NEG_INF; }

  // prologue: 2-deep prefetch
  stage_k_chunk(KT[0], gk, 0, tid);
  stage_k_chunk(KT[1], gk, 1, tid);

  for (int c = 0; c < 8; ++c) {
    if (c < 7) {
      asm volatile("s_waitcnt vmcnt(2)" ::: "memory");
    } else {
      asm volatile("s_waitcnt vmcnt(0)" ::: "memory");
    }
    __builtin_amdgcn_sched_barrier(0);
    __builtin_amdgcn_s_barrier();
    if (c + 2 < 8) stage_k_chunk(KT[(c + 2) % 3], gk, c + 2, tid);

    const ushort_t* kt = KT[c % 3];
    const int sw = (lr & 7) << 3;
    const uint_t jb0 = (uint_t)(c * 128) + (uint_t)(lg * 4);
#pragma unroll
    for (int jtl = 0; jtl < 8; ++jtl) {
      const int rbase = (jtl * 16 + lr) * 64;
      short8 k0 = *(const short8*)&kt[rbase + ((lg << 3) ^ sw)];
      short8 k1 = *(const short8*)&kt[rbase + (((lg + 4) << 3) ^ sw)];
      f32x4 aA = {0.f, 0.f, 0.f, 0.f};
      aA = __builtin_amdgcn_mfma_f32_16x16x32_bf16(k0, qh[0], aA, 0, 0, 0);
      aA = __builtin_amdgcn_mfma_f32_16x16x32_bf16(k1, qh[1], aA, 0, 0, 0);
      const uint_t jbase = jb0 + (uint_t)(jtl * 16);
      float ca = packkey(aA[0], jbase);
      float cb = packkey(aA[1], jbase + 1);
      float cc = packkey(aA[2], jbase + 2);
      float cd = packkey(aA[3], jbase + 3);
      sort4f(ca, cb, cc, cd);
      if (jtl & 1)
        merge44f(Kb[0], Kb[1], Kb[2], Kb[3], ca, cb, cc, cd);
      else
        merge44f(Ka[0], Ka[1], Ka[2], Ka[3], ca, cb, cc, cd);
    }
  }

  // intra-wave merge of the 4 lane-groups (disjoint j subsets) per q-row
#pragma unroll
  for (int mask = 16; mask <= 32; mask <<= 1) {
    float a0 = __shfl_xor(Ka[0], mask), a1 = __shfl_xor(Ka[1], mask);
    float a2 = __shfl_xor(Ka[2], mask), a3 = __shfl_xor(Ka[3], mask);
    merge44f(Ka[0], Ka[1], Ka[2], Ka[3], a0, a1, a2, a3);
    float b0 = __shfl_xor(Kb[0], mask), b1 = __shfl_xor(Kb[1], mask);
    float b2 = __shfl_xor(Kb[2], mask), b3 = __shfl_xor(Kb[3], mask);
    merge44f(Kb[0], Kb[1], Kb[2], Kb[3], b0, b1, b2, b3);
  }
  if (l < 16) {
    int r = w * 16 + l;
#pragma unroll
    for (int t = 0; t < 4; ++t) {
      kLp[r][t] = __float_as_uint(Ka[t]);
      kLp[r][4 + t] = __float_as_uint(Kb[t]);
    }
  }
  // wave-local from here on (each wave reads only its own rows' tables)

  // ---- Stage B: rescore 8 finalists/row from fp32 qf/kf
  {
    const int cand = l >> 3, dg = l & 7;
#pragma unroll 4
    for (int rr = 0; rr < 16; ++rr) {
      int r = w * 16 + rr;
      int j = (int)(kLp[r][cand] & 1023u);
      int qa = bhbase + (rg * 128 + r) * 64 + dg * 8;
      int ka = bhbase + j * 64 + dg * 8;
      f32x4 q0 = *(const f32x4*)(qf + qa);
      f32x4 q1 = *(const f32x4*)(qf + qa + 4);
      f32x4 k0 = *(const f32x4*)(kf + ka);
      f32x4 k1 = *(const f32x4*)(kf + ka + 4);
      float s = q0[0] * k0[0];
      s = fmaf(q0[1], k0[1], s);
      s = fmaf(q0[2], k0[2], s);
      s = fmaf(q0[3], k0[3], s);
      s = fmaf(q1[0], k1[0], s);
      s = fmaf(q1[1], k1[1], s);
      s = fmaf(q1[2], k1[2], s);
      s = fmaf(q1[3], k1[3], s);
      s += __shfl_xor(s, 1);
      s += __shfl_xor(s, 2);
      s += __shfl_xor(s, 4);
      if (dg == 0) scS[r][cand] = s;
    }
  }

  // per-row final top-4 + softmax (lanes 0..15 = wave's 16 rows)
  if (l < 16) {
    int r = w * 16 + l;
    float s0 = NEG_INF, s1 = NEG_INF, s2 = NEG_INF, s3 = NEG_INF;
    int i0 = 0, i1 = 0, i2 = 0, i3 = 0;
#pragma unroll
    for (int c8 = 0; c8 < 8; ++c8)
      insert4(scS[r][c8], (int)(kLp[r][c8] & 1023u), s0, s1, s2, s3, i0, i1,
              i2, i3);
    float m = s0;
    float e0 = expf(s0 - m), e1 = expf(s1 - m);
    float e2 = expf(s2 - m), e3 = expf(s3 - m);
    float inv = 1.f / (e0 + e1 + e2 + e3);
    wgt[r][0] = e0 * inv; wgt[r][1] = e1 * inv;
    wgt[r][2] = e2 * inv; wgt[r][3] = e3 * inv;
    widx[r][0] = i0; widx[r][1] = i1; widx[r][2] = i2; widx[r][3] = i3;
  }

  // ---- Stage C: lane = d; gather bf16 V, weight, multiply q, accumulate
  const ushort_t* vbh = vbf + bhbase;
  float acc = 0.f;
#pragma unroll 4
  for (int rr = 0; rr < 16; ++rr) {
    int r = w * 16 + rr;
    float w0 = wgt[r][0], w1 = wgt[r][1], w2 = wgt[r][2], w3 = wgt[r][3];
    int x0 = widx[r][0], x1 = widx[r][1], x2 = widx[r][2], x3 = widx[r][3];
    float wv = w0 * bf2f(vbh[x0 * 64 + l]);
    wv = fmaf(w1, bf2f(vbh[x1 * 64 + l]), wv);
    wv = fmaf(w2, bf2f(vbh[x2 * 64 + l]), wv);
    wv = fmaf(w3, bf2f(vbh[x3 * 64 + l]), wv);
    acc = fmaf(wv, qf[bhbase + (rg * 128 + r) * 64 + l], acc);
  }
  atomicAdd(&out[(bh >> 3) * Cc + l * Hc + (bh & 7)], acc);
}

// ---------------------------------------------------------------- launch
extern "C" void kernel_launch(void* const* d_in, const int* in_sizes, int n_in,
                              void* d_out, int out_size, void* d_ws,
                              size_t ws_size, hipStream_t stream) {
  (void)in_sizes; (void)n_in; (void)out_size; (void)ws_size;
  const float* x = (const float*)d_in[0];
  const float* wq = (const float*)d_in[1];
  const float* bias = (const float*)d_in[2];
  float* out = (float*)d_out;

  float* kf = (float*)d_ws;                 // QSZ f32  (16.8 MB)
  float* qf = kf + QSZ;                     // QSZ f32  (16.8 MB)
  ushort_t* vbf = (ushort_t*)(qf + QSZ);    // QSZ bf16 (8.4 MB)
  ushort_t* khi = vbf + QSZ;                // QSZ bf16 (8.4 MB)
  ushort_t* qhi = khi + QSZ;                // QSZ bf16 (8.4 MB)
  ushort_t* xth = qhi + QSZ;                // XTSZ bf16 (8.4 MB)
  ushort_t* wth = xth + XTSZ;               // WTSZ bf16 (1.6 MB)
  ushort_t* wtl = wth + WTSZ;               // WTSZ bf16 (1.6 MB)

  conv_x<<<dim3(16, 8, 8), 256, 0, stream>>>(x, xth, out);
  conv_w<<<dim3(24, 8), 256, 0, stream>>>(wq, wth, wtl);
  qkv_gemm_mfma<<<dim3(64, 12), 256, 0, stream>>>(xth, wth, wtl, bias, vbf,
                                                  kf, qf, khi, qhi);
  attn_topk_mfma<<<dim3(512), 512, 0, stream>>>(khi, qhi, kf, qf, vbf, out);
}

// Round 20
// 92.487 us; speedup vs baseline: 1.0511x; 1.0511x over previous
//
#include <hip/hip_runtime.h>

#define NEG_INF (-3.402823466e+38f)

constexpr int Bc = 8, Cc = 512, Hc = 8, Dc = 64, Nc = 1024;
constexpr size_t QSZ = (size_t)Bc * Hc * Nc * Dc;  // 4,194,304 elements
constexpr size_t XTSZ = (size_t)8192 * 512;        // = QSZ
constexpr size_t WTSZ = (size_t)1536 * 512;

typedef __attribute__((ext_vector_type(8))) short short8;
typedef __attribute__((ext_vector_type(4))) float f32x4;
typedef unsigned short ushort_t;
typedef unsigned int uint_t;

// ------------------------------------------------------------ bf16 helpers
__device__ __forceinline__ ushort_t f2bf(float x) {
  uint_t u = __float_as_uint(x);
  u += 0x7FFFu + ((u >> 16) & 1u);  // round-to-nearest-even
  return (ushort_t)(u >> 16);
}
__device__ __forceinline__ float bf2f(ushort_t h) {
  return __uint_as_float(((uint_t)h) << 16);
}

// ------------------------------------- transpose x -> xt (bf16) + zero out
__global__ __launch_bounds__(256) void conv_x(const float* __restrict__ x,
                                              ushort_t* __restrict__ xh,
                                              float* __restrict__ out) {
  __shared__ float t[64][65];
  const int b = blockIdx.z, c0 = blockIdx.y * 64, n0 = blockIdx.x * 64;
  const int tid = threadIdx.x;
  const int lc = tid & 63, lr = tid >> 6;
  int fb = (blockIdx.z * 8 + blockIdx.y) * 16 + blockIdx.x;
  if (fb < 16) out[fb * 256 + tid] = 0.f;
#pragma unroll
  for (int i = 0; i < 16; ++i) {
    int cc = lr + i * 4;
    t[cc][lc] = x[((size_t)(b * 512 + c0 + cc)) * 1024 + n0 + lc];
  }
  __syncthreads();
#pragma unroll
  for (int i = 0; i < 16; ++i) {
    int nn = lr + i * 4;
    xh[((size_t)(b * 1024 + n0 + nn)) * 512 + c0 + lc] = f2bf(t[lc][nn]);
  }
}

// ---------------------------------- transpose+split W -> wt hi/lo (bf16 x2)
__global__ __launch_bounds__(256) void conv_w(const float* __restrict__ wq,
                                              ushort_t* __restrict__ wh,
                                              ushort_t* __restrict__ wl) {
  __shared__ float t[64][65];
  const int c0 = blockIdx.y * 64, j0 = blockIdx.x * 64;
  const int tid = threadIdx.x;
  const int lj = tid & 63, lr = tid >> 6;
#pragma unroll
  for (int i = 0; i < 16; ++i) {
    int cc = lr + i * 4;
    t[cc][lj] = wq[(size_t)(c0 + cc) * 1536 + j0 + lj];
  }
  __syncthreads();
#pragma unroll
  for (int i = 0; i < 16; ++i) {
    int jj = lr + i * 4;
    float v = t[lj][jj];  // = W[c0+lj][j0+jj]
    ushort_t h = f2bf(v);
    size_t o = (size_t)(j0 + jj) * 512 + c0 + lj;
    wh[o] = h;
    wl[o] = f2bf(v - bf2f(h));
  }
}

// ------------------------------------------------------ async stage helper
__device__ __forceinline__ void stage_tile(ushort_t* lds, const ushort_t* g,
                                           int tid) {
  typedef const __attribute__((address_space(1))) unsigned int GU;
  typedef __attribute__((address_space(3))) unsigned int LU;
  {
    int l = tid, r = l >> 2, c = (l & 3) * 8;
    __builtin_amdgcn_global_load_lds((GU*)(g + (size_t)r * 512 + c),
                                     (LU*)(lds + (size_t)l * 8), 16, 0, 0);
  }
  {
    int l = tid + 256, r = l >> 2, c = (l & 3) * 8;
    __builtin_amdgcn_global_load_lds((GU*)(g + (size_t)r * 512 + c),
                                     (LU*)(lds + (size_t)l * 8), 16, 0, 0);
  }
}

// ---------------------------------------------------------------- QKV GEMM
// 2-pass: C = x_bf * (W_hi + W_lo). Value error ~0.002 (x rounding only).
__global__ __launch_bounds__(256) void qkv_gemm_mfma(
    const ushort_t* __restrict__ xth, const ushort_t* __restrict__ wth,
    const ushort_t* __restrict__ wtl, const float* __restrict__ bias,
    float* __restrict__ vbuf, float* __restrict__ kf, float* __restrict__ qf,
    ushort_t* __restrict__ khi, ushort_t* __restrict__ qhi) {
  __shared__ __align__(16) ushort_t Ah[128 * 32];
  __shared__ __align__(16) ushort_t Bh[128 * 32];
  __shared__ __align__(16) ushort_t Bl[128 * 32];

  const int m0 = blockIdx.x * 128, j0 = blockIdx.y * 128;
  const int tid = threadIdx.x;
  const int w = tid >> 6, l = tid & 63;
  const int lr = l & 15, lg = l >> 4;
  const int wr = w >> 1, wc = w & 1;

  f32x4 acc[4][4];
#pragma unroll
  for (int i = 0; i < 4; ++i)
#pragma unroll
    for (int j = 0; j < 4; ++j) acc[i][j] = (f32x4){0.f, 0.f, 0.f, 0.f};

  const ushort_t* xa = xth + (size_t)m0 * 512;
  const ushort_t* wa = wth + (size_t)j0 * 512;
  const ushort_t* wb = wtl + (size_t)j0 * 512;

  for (int s = 0; s < 16; ++s) {
    const int k0 = s * 32;
    stage_tile(Ah, xa + k0, tid);
    stage_tile(Bh, wa + k0, tid);
    stage_tile(Bl, wb + k0, tid);
    __syncthreads();  // drains vmcnt -> tiles resident

    short8 ah[4], bh[4], bl[4];
#pragma unroll
    for (int mi = 0; mi < 4; ++mi)
      ah[mi] = *(const short8*)&Ah[(wr * 64 + mi * 16 + lr) * 32 + lg * 8];
#pragma unroll
    for (int ji = 0; ji < 4; ++ji) {
      int ro = (wc * 64 + ji * 16 + lr) * 32 + lg * 8;
      bh[ji] = *(const short8*)&Bh[ro];
      bl[ji] = *(const short8*)&Bl[ro];
    }
#pragma unroll
    for (int mi = 0; mi < 4; ++mi)
#pragma unroll
      for (int ji = 0; ji < 4; ++ji) {
        acc[mi][ji] = __builtin_amdgcn_mfma_f32_16x16x32_bf16(
            ah[mi], bh[ji], acc[mi][ji], 0, 0, 0);
        acc[mi][ji] = __builtin_amdgcn_mfma_f32_16x16x32_bf16(
            ah[mi], bl[ji], acc[mi][ji], 0, 0, 0);
      }
    __syncthreads();
  }

  const int which = j0 >> 9;
  const int hh = ((j0 >> 6) + wc) & 7;
  float bias_r[4];
#pragma unroll
  for (int ji = 0; ji < 4; ++ji) bias_r[ji] = bias[j0 + wc * 64 + ji * 16 + lr];

#pragma unroll
  for (int mi = 0; mi < 4; ++mi)
#pragma unroll
    for (int t = 0; t < 4; ++t) {
      int m = m0 + wr * 64 + mi * 16 + lg * 4 + t;
      int b = m >> 10, n = m & 1023;
      size_t rb = ((size_t)(b * 8 + hh) << 16) + (size_t)n * 64;
#pragma unroll
      for (int ji = 0; ji < 4; ++ji) {
        float val = acc[mi][ji][t] + bias_r[ji];
        int dd = ji * 16 + lr;
        if (which == 2) {
          vbuf[rb + dd] = val;
        } else if (which == 0) {
          qhi[rb + dd] = f2bf(val);
          qf[rb + dd] = val;
        } else {
          khi[rb + dd] = f2bf(val);
          kf[rb + dd] = val;
        }
      }
    }
}

// -------------------------------------------- float-domain packed-key top-4
__device__ __forceinline__ float packkey(float s, uint_t j) {
  return __uint_as_float((__float_as_uint(s) & 0xFFFFFC00u) | j);
}

// sort 4 keys descending (5-comparator network, depth 3)
__device__ __forceinline__ void sort4f(float& a, float& b, float& c,
                                       float& d) {
  float t;
  t = fmaxf(a, b); b = fminf(a, b); a = t;
  t = fmaxf(c, d); d = fminf(c, d); c = t;
  t = fmaxf(a, c); c = fminf(a, c); a = t;
  t = fmaxf(b, d); d = fminf(b, d); b = t;
  t = fmaxf(b, c); c = fminf(b, c); b = t;
}

// state s0>=s1>=s2>=s3; cand a>=b>=c>=d. Bitonic keep-top-4 + resort.
__device__ __forceinline__ void merge44f(float& s0, float& s1, float& s2,
                                         float& s3, float a, float b, float c,
                                         float d) {
  s0 = fmaxf(s0, d); s1 = fmaxf(s1, c); s2 = fmaxf(s2, b); s3 = fmaxf(s3, a);
  float t;
  t = fmaxf(s0, s2); s2 = fminf(s0, s2); s0 = t;
  t = fmaxf(s1, s3); s3 = fminf(s1, s3); s1 = t;
  t = fmaxf(s0, s1); s1 = fminf(s0, s1); s0 = t;
  t = fmaxf(s2, s3); s3 = fminf(s2, s3); s2 = t;
}

// -------------------------------------------------------- float insert4
__device__ __forceinline__ void insert4(float sc, int jv, float& s0, float& s1,
                                        float& s2, float& s3, int& i0, int& i1,
                                        int& i2, int& i3) {
  bool c = sc > s3;
  s3 = c ? sc : s3; i3 = c ? jv : i3;
  c = s3 > s2;
  { float t = c ? s2 : s3; s2 = c ? s3 : s2; s3 = t;
    int q = c ? i2 : i3; i2 = c ? i3 : i2; i3 = q; }
  c = s2 > s1;
  { float t = c ? s1 : s2; s1 = c ? s2 : s1; s2 = t;
    int q = c ? i1 : i2; i1 = c ? i2 : i1; i2 = q; }
  c = s1 > s0;
  { float t = c ? s0 : s1; s0 = c ? s1 : s0; s1 = t;
    int q = c ? i0 : i1; i0 = c ? i1 : i0; i1 = q; }
}

// ------------------------------------ stage one 128j x 64d K chunk (16 KB)
// LDS dest linear (global_load_lds constraint); XOR swizzle applied to the
// GLOBAL source column (m173 pattern); readers XOR the column group.
__device__ __forceinline__ void stage_k_chunk(ushort_t* kt,
                                              const ushort_t* gk, int chunk,
                                              int tid) {
  typedef const __attribute__((address_space(1))) unsigned int GU;
  typedef __attribute__((address_space(3))) unsigned int LU;
#pragma unroll
  for (int ri = 0; ri < 2; ++ri) {
    int p = ri * 512 + tid;      // 0..1023
    int row = p >> 3;            // 0..127 (j within chunk)
    int colu = (p & 7) << 3;     // ushort col: 0,8,..,56
    int srcu = (chunk * 128 + row) * 64 + (colu ^ ((row & 7) << 3));
    __builtin_amdgcn_global_load_lds((GU*)(gk + srcu),
                                     (LU*)(kt + (size_t)p * 8), 16, 0, 0);
  }
}

// ---------------------------------------------------------------- fused attn
// R16 structure (grid 512, block=128 rows, 8 waves, wave owns 16 rows and
// scans ALL 1024 j) with the chunk loop converted from
// {stage -> __syncthreads (vmcnt(0) drain)} to the T3/T4 counted-vmcnt
// pipeline: 3 buffers, 2-deep prefetch, s_waitcnt vmcnt(2) + raw s_barrier
// per chunk (vmcnt(0) only on the last). The prefetch for c+2 is issued
// AFTER the barrier (its buffer held chunk c-1; all waves provably past it)
// and never gets drained at a barrier -> ~2 chunk-scans of latency cover.
// launch_bounds MUST stay (512,6)/(512,4)-class; (512,8) crushes VGPR (R15).
__global__ __launch_bounds__(512, 6) void attn_topk_mfma(
    const ushort_t* __restrict__ khi, const ushort_t* __restrict__ qhi,
    const float* __restrict__ kf, const float* __restrict__ qf,
    const float* __restrict__ vg, float* __restrict__ out) {
  __shared__ __align__(16) ushort_t KT[3][128 * 64];  // 3 x 16 KB
  __shared__ uint_t kLp[128][9];  // pad 9: kill stride-8 bank conflicts
  __shared__ float scS[128][9];
  __shared__ float wgt[128][4];
  __shared__ int widx[128][4];

  const int bid = blockIdx.x;
  const int bh = bid & 63;
  const int rg = bid >> 6;  // 0..7
  const int tid = threadIdx.x;
  const int w = tid >> 6, l = tid & 63;
  const int lg = l >> 4, lr = l & 15;

  const int bhbase = bh << 16;           // bh * 1024 * 64
  const int rowbase = rg * 128 + w * 16; // wave's first q-row (global in bh)
  const ushort_t* gk = khi + bhbase;

  // Q fragments: 1 rowset x 2 d-chunks
  short8 qh[2];
#pragma unroll
  for (int c2 = 0; c2 < 2; ++c2)
    qh[c2] = *(const short8*)(qhi + bhbase + (rowbase + lr) * 64 + c2 * 32 +
                              lg * 8);

  float Ka[4], Kb[4];
#pragma unroll
  for (int t = 0; t < 4; ++t) { Ka[t] = NEG_INF; Kb[t] = NEG_INF; }

  // prologue: 2-deep prefetch
  stage_k_chunk(KT[0], gk, 0, tid);
  stage_k_chunk(KT[1], gk, 1, tid);

  for (int c = 0; c < 8; ++c) {
    // wait own stage(c) loads (leave stage(c+1) in flight), then barrier:
    // after it, ALL waves' stage(c) landed and all waves are done reading
    // buffer (c+2)%3 (they scanned chunk c-1 from it before arriving).
    if (c < 7) {
      asm volatile("s_waitcnt vmcnt(2)" ::: "memory");
    } else {
      asm volatile("s_waitcnt vmcnt(0)" ::: "memory");
    }
    __builtin_amdgcn_sched_barrier(0);
    __builtin_amdgcn_s_barrier();
    if (c + 2 < 8) stage_k_chunk(KT[(c + 2) % 3], gk, c + 2, tid);

    const ushort_t* kt = KT[c % 3];
    const int sw = (lr & 7) << 3;
    const uint_t jb0 = (uint_t)(c * 128) + (uint_t)(lg * 4);
#pragma unroll
    for (int jtl = 0; jtl < 8; ++jtl) {
      const int rbase = (jtl * 16 + lr) * 64;
      short8 k0 = *(const short8*)&kt[rbase + ((lg << 3) ^ sw)];
      short8 k1 = *(const short8*)&kt[rbase + (((lg + 4) << 3) ^ sw)];
      f32x4 aA = {0.f, 0.f, 0.f, 0.f};
      aA = __builtin_amdgcn_mfma_f32_16x16x32_bf16(k0, qh[0], aA, 0, 0, 0);
      aA = __builtin_amdgcn_mfma_f32_16x16x32_bf16(k1, qh[1], aA, 0, 0, 0);
      const uint_t jbase = jb0 + (uint_t)(jtl * 16);
      float ca = packkey(aA[0], jbase);
      float cb = packkey(aA[1], jbase + 1);
      float cc = packkey(aA[2], jbase + 2);
      float cd = packkey(aA[3], jbase + 3);
      sort4f(ca, cb, cc, cd);
      if (jtl & 1)
        merge44f(Kb[0], Kb[1], Kb[2], Kb[3], ca, cb, cc, cd);
      else
        merge44f(Ka[0], Ka[1], Ka[2], Ka[3], ca, cb, cc, cd);
    }
  }

  // intra-wave merge of the 4 lane-groups (disjoint j subsets) per q-row
#pragma unroll
  for (int mask = 16; mask <= 32; mask <<= 1) {
    float a0 = __shfl_xor(Ka[0], mask), a1 = __shfl_xor(Ka[1], mask);
    float a2 = __shfl_xor(Ka[2], mask), a3 = __shfl_xor(Ka[3], mask);
    merge44f(Ka[0], Ka[1], Ka[2], Ka[3], a0, a1, a2, a3);
    float b0 = __shfl_xor(Kb[0], mask), b1 = __shfl_xor(Kb[1], mask);
    float b2 = __shfl_xor(Kb[2], mask), b3 = __shfl_xor(Kb[3], mask);
    merge44f(Kb[0], Kb[1], Kb[2], Kb[3], b0, b1, b2, b3);
  }
  if (l < 16) {
    int r = w * 16 + l;
#pragma unroll
    for (int t = 0; t < 4; ++t) {
      kLp[r][t] = __float_as_uint(Ka[t]);
      kLp[r][4 + t] = __float_as_uint(Kb[t]);
    }
  }
  // wave-local from here on (each wave reads only its own rows' tables)

  // ---- Stage B: rescore 8 finalists/row from fp32 qf/kf
  // lane = cand(0..7)*8 + dg(0..7); wave rescores its own 16 rows
  {
    const int cand = l >> 3, dg = l & 7;
#pragma unroll 4
    for (int rr = 0; rr < 16; ++rr) {
      int r = w * 16 + rr;
      int j = (int)(kLp[r][cand] & 1023u);
      int qa = bhbase + (rg * 128 + r) * 64 + dg * 8;
      int ka = bhbase + j * 64 + dg * 8;
      f32x4 q0 = *(const f32x4*)(qf + qa);
      f32x4 q1 = *(const f32x4*)(qf + qa + 4);
      f32x4 k0 = *(const f32x4*)(kf + ka);
      f32x4 k1 = *(const f32x4*)(kf + ka + 4);
      float s = q0[0] * k0[0];
      s = fmaf(q0[1], k0[1], s);
      s = fmaf(q0[2], k0[2], s);
      s = fmaf(q0[3], k0[3], s);
      s = fmaf(q1[0], k1[0], s);
      s = fmaf(q1[1], k1[1], s);
      s = fmaf(q1[2], k1[2], s);
      s = fmaf(q1[3], k1[3], s);
      s += __shfl_xor(s, 1);
      s += __shfl_xor(s, 2);
      s += __shfl_xor(s, 4);
      if (dg == 0) scS[r][cand] = s;
    }
  }

  // per-row final top-4 + softmax (lanes 0..15 = wave's 16 rows)
  if (l < 16) {
    int r = w * 16 + l;
    float s0 = NEG_INF, s1 = NEG_INF, s2 = NEG_INF, s3 = NEG_INF;
    int i0 = 0, i1 = 0, i2 = 0, i3 = 0;
#pragma unroll
    for (int c8 = 0; c8 < 8; ++c8)
      insert4(scS[r][c8], (int)(kLp[r][c8] & 1023u), s0, s1, s2, s3, i0, i1,
              i2, i3);
    float m = s0;
    float e0 = expf(s0 - m), e1 = expf(s1 - m);
    float e2 = expf(s2 - m), e3 = expf(s3 - m);
    float inv = 1.f / (e0 + e1 + e2 + e3);
    wgt[r][0] = e0 * inv; wgt[r][1] = e1 * inv;
    wgt[r][2] = e2 * inv; wgt[r][3] = e3 * inv;
    widx[r][0] = i0; widx[r][1] = i1; widx[r][2] = i2; widx[r][3] = i3;
  }

  // ---- Stage C: lane = d; gather V, weight, multiply q, accumulate rows
  const float* vbh = vg + (size_t)bhbase;
  float acc = 0.f;
#pragma unroll 4
  for (int rr = 0; rr < 16; ++rr) {
    int r = w * 16 + rr;
    float w0 = wgt[r][0], w1 = wgt[r][1], w2 = wgt[r][2], w3 = wgt[r][3];
    int x0 = widx[r][0], x1 = widx[r][1], x2 = widx[r][2], x3 = widx[r][3];
    float wv = w0 * vbh[(size_t)x0 * 64 + l];
    wv = fmaf(w1, vbh[(size_t)x1 * 64 + l], wv);
    wv = fmaf(w2, vbh[(size_t)x2 * 64 + l], wv);
    wv = fmaf(w3, vbh[(size_t)x3 * 64 + l], wv);
    acc = fmaf(wv, qf[bhbase + (rg * 128 + r) * 64 + l], acc);
  }
  atomicAdd(&out[(bh >> 3) * Cc + l * Hc + (bh & 7)], acc);
}

// ---------------------------------------------------------------- launch
extern "C" void kernel_launch(void* const* d_in, const int* in_sizes, int n_in,
                              void* d_out, int out_size, void* d_ws,
                              size_t ws_size, hipStream_t stream) {
  (void)in_sizes; (void)n_in; (void)out_size; (void)ws_size;
  const float* x = (const float*)d_in[0];
  const float* wq = (const float*)d_in[1];
  const float* bias = (const float*)d_in[2];
  float* out = (float*)d_out;

  float* vbuf = (float*)d_ws;               // QSZ f32  (16.8 MB)
  float* kf = vbuf + QSZ;                   // QSZ f32  (16.8 MB)
  float* qf = kf + QSZ;                     // QSZ f32  (16.8 MB)
  ushort_t* khi = (ushort_t*)(qf + QSZ);    // QSZ bf16 (8.4 MB)
  ushort_t* qhi = khi + QSZ;                // QSZ bf16 (8.4 MB)
  ushort_t* xth = qhi + QSZ;                // XTSZ bf16 (8.4 MB)
  ushort_t* wth = xth + XTSZ;               // WTSZ bf16 (1.6 MB)
  ushort_t* wtl = wth + WTSZ;               // WTSZ bf16 (1.6 MB)

  conv_x<<<dim3(16, 8, 8), 256, 0, stream>>>(x, xth, out);
  conv_w<<<dim3(24, 8), 256, 0, stream>>>(wq, wth, wtl);
  qkv_gemm_mfma<<<dim3(64, 12), 256, 0, stream>>>(xth, wth, wtl, bias, vbuf,
                                                  kf, qf, khi, qhi);
  attn_topk_mfma<<<dim3(512), 512, 0, stream>>>(khi, qhi, kf, qf, vbuf, out);
}